// Round 4
// baseline (633.509 us; speedup 1.0000x reference)
//
#include <hip/hip_runtime.h>
#include <stdint.h>

#define N_GRAPHS 16
#define NODES_PER 420
#define NN (N_GRAPHS * NODES_PER)   // 6720 nodes
#define MP 6784                     // padded rows: 53 * 128
#define EE (NN * 8)                 // 53760 edges
#define IN_DIM 2048
#define NCAT1 8192                  // 4 * 2048  (Q|K|V|S)
#define NCAT2 256                   // 4 * 64
#define KDIM 2048

typedef __bf16 bf16x8 __attribute__((ext_vector_type(8)));
typedef float f32x4 __attribute__((ext_vector_type(4)));
typedef unsigned short u16x8 __attribute__((ext_vector_type(8)));

__device__ __forceinline__ unsigned short f2bf(float f) {
  unsigned u = __float_as_uint(f);
  u += 0x7FFFu + ((u >> 16) & 1u);   // round-to-nearest-even
  return (unsigned short)(u >> 16);
}
__device__ __forceinline__ float bf2f(unsigned short h) {
  return __uint_as_float(((unsigned)h) << 16);
}

// async global->LDS, 16B per lane. LDS dest must be wave-uniform base + lane*16.
__device__ __forceinline__ void gl2lds16(const void* g, const void* l) {
  __builtin_amdgcn_global_load_lds(
      (const __attribute__((address_space(1))) void*)(uintptr_t)g,
      (__attribute__((address_space(3))) void*)(unsigned int)(uintptr_t)l,
      16, 0, 0);
}

// ------- prep: zero counts, concat bias1/bias2, init f1 with bias -----------
__global__ void prep_k(int* cnt, float* bcat1, float* bcat2, float* f1,
                       const float* bq1, const float* bk1, const float* bv1, const float* bs1,
                       const float* bq2, const float* bk2, const float* bv2, const float* bs2,
                       const float* bfc1) {
  int i = blockIdx.x * 256 + threadIdx.x;
  if (i < NN) cnt[i] = 0;
  if (i < NCAT1) {
    const float* p = i < 2048 ? bq1 : i < 4096 ? bk1 : i < 6144 ? bv1 : bs1;
    bcat1[i] = p[i & 2047];
  }
  if (i < NCAT2) {
    const float* p = i < 64 ? bq2 : i < 128 ? bk2 : i < 192 ? bv2 : bs2;
    bcat2[i] = p[i & 63];
  }
  if (i < 16 * 256) f1[i] = bfc1[i & 255];
}

// ---------------- CSR build --------------------------------------------------
__global__ void cnt_edges_k(const int* __restrict__ ei, int* __restrict__ cnt) {
  int e = blockIdx.x * 256 + threadIdx.x;
  if (e < EE) atomicAdd(&cnt[ei[EE + e]], 1);
}

// 256 threads, thread owns 27 nodes; shfl wave scan + cross-wave LDS scan.
__global__ __launch_bounds__(256) void scan_offs_k(const int* __restrict__ cnt,
                                                   int* __restrict__ offs,
                                                   int* __restrict__ cursor) {
  const int t = threadIdx.x;
  const int base = t * 27;
  int c[27];
  int s = 0;
#pragma unroll
  for (int j = 0; j < 27; j++) {
    int idx = base + j;
    c[j] = idx < NN ? cnt[idx] : 0;
    s += c[j];
  }
  const int lane = t & 63, w = t >> 6;
  int pfx = s;  // inclusive wave scan
#pragma unroll
  for (int d = 1; d < 64; d <<= 1) {
    int v = __shfl_up(pfx, d, 64);
    if (lane >= d) pfx += v;
  }
  __shared__ int wtot[4];
  if (lane == 63) wtot[w] = pfx;
  __syncthreads();
  int add = 0;
#pragma unroll
  for (int i = 0; i < 4; i++)
    if (i < w) add += wtot[i];
  int run = add + pfx - s;  // exclusive prefix
#pragma unroll
  for (int j = 0; j < 27; j++) {
    int idx = base + j;
    if (idx < NN) { offs[idx] = run; cursor[idx] = run; }
    run += c[j];
  }
  if (t == 255) offs[NN] = add + pfx;  // grand total
}

__global__ void scatter_k(const int* __restrict__ ei, int* __restrict__ cursor,
                          int* __restrict__ psrc) {
  int e = blockIdx.x * 256 + threadIdx.x;
  if (e < EE) {
    int d = ei[EE + e];
    int pos = atomicAdd(&cursor[d], 1);
    psrc[pos] = ei[e];
  }
}

// ------- positional-embedding add fp32->bf16 --------------------------------
__global__ void pe_add_k(const float* __restrict__ x, const int* __restrict__ conn,
                         const float* __restrict__ npe, const float* __restrict__ lpe,
                         const float* __restrict__ gpe, unsigned short* __restrict__ h0) {
  const int n = blockIdx.x, t = threadIdx.x;
  const int c = conn[n];
  const float4* x4 = (const float4*)(x + (size_t)n * IN_DIM);
  const float4* n4 = (const float4*)(npe + (size_t)(n % NODES_PER) * IN_DIM);
  const float4* l4 = (const float4*)(lpe + (size_t)(c - 1) * IN_DIM);
  const float4* g4 = (const float4*)(gpe + (size_t)(c <= 2 ? 0 : 1) * IN_DIM);
  ushort4* o4 = (ushort4*)(h0 + (size_t)n * IN_DIM);
#pragma unroll
  for (int i = 0; i < 2; i++) {
    int idx = i * 256 + t;
    float4 a = x4[idx], b = n4[idx], cc = l4[idx], d = g4[idx];
    ushort4 o;
    o.x = f2bf(a.x + b.x + cc.x + d.x);
    o.y = f2bf(a.y + b.y + cc.y + d.y);
    o.z = f2bf(a.z + b.z + cc.z + d.z);
    o.w = f2bf(a.w + b.w + cc.w + d.w);
    o4[idx] = o;
  }
}

// ---------------- weight transpose + bf16 convert: W[K,Nc] -> Wt[Nc,K] -------
__global__ void transw_k(const float* Wq1, const float* Wk1, const float* Wv1, const float* Ws1,
                         const float* Wq2, const float* Wk2, const float* Wv2, const float* Ws2,
                         unsigned short* __restrict__ o1, unsigned short* __restrict__ o2) {
  __shared__ float tile[32][33];
  const int z = blockIdx.z;
  const float* W;
  unsigned short* o;
  int n0, Ncol;
  const int k0 = blockIdx.y * 32;
  if (z < 4) {
    W = z == 0 ? Wq1 : z == 1 ? Wk1 : z == 2 ? Wv1 : Ws1;
    o = o1 + (size_t)z * 2048 * KDIM;
    n0 = blockIdx.x * 32; Ncol = 2048;
  } else {
    if (blockIdx.x >= 8) return;
    const int m = blockIdx.x >> 1;
    W = m == 0 ? Wq2 : m == 1 ? Wk2 : m == 2 ? Wv2 : Ws2;
    o = o2 + (size_t)m * 64 * KDIM;
    n0 = (blockIdx.x & 1) * 32; Ncol = 64;
  }
  const int tx = threadIdx.x, ty = threadIdx.y;
#pragma unroll
  for (int r = 0; r < 4; r++)
    tile[ty + r * 8][tx] = W[(size_t)(k0 + ty + r * 8) * Ncol + n0 + tx];
  __syncthreads();
#pragma unroll
  for (int r = 0; r < 4; r++)
    o[(size_t)(n0 + ty + r * 8) * KDIM + k0 + tx] = f2bf(tile[tx][ty + r * 8]);
}

// ---------------- bf16 MFMA GEMM, C = A @ Bt^T (+bias) -----------------------
// A [Mpad,K] bf16 row-major, Bt [N,K] bf16 row-major. BK=64, 2-barrier K-loop,
// global_load_lds x16B with k-chunk XOR swizzle (bank-conflict-free ds_read).
// OUTF==0: C bf16 = acc + bias, NT store. OUTF==1: C f32 split-K partials at
// C + z*MP*Nsz, NT store (combined later).
template <int BM, int BN, int OUTF>
__launch_bounds__(256, 4)
__global__ void gemm_bt_k(const unsigned short* __restrict__ A,
                          const unsigned short* __restrict__ Bt,
                          const float* __restrict__ bias, void* __restrict__ C,
                          int Nsz, int K, int kIters) {
  constexpr int BK = 64;
  constexpr int WTM = BM / 32, WTN = BN / 32;  // MFMA tiles per wave (2x2 wave grid)
  constexpr int RA = BM / 32, RB = BN / 32;    // 4KB staging rounds (32 rows each)
  __shared__ __align__(16) unsigned short lA[BM * BK];
  __shared__ __align__(16) unsigned short lB[BN * BK];
  const int t = threadIdx.x;
  const int w = t >> 6, lane = t & 63;
  const int wm = w >> 1, wn = w & 1;
  const int quad = lane >> 4, l16 = lane & 15;
  const int m0 = blockIdx.y * BM, n0 = blockIdx.x * BN;

  f32x4 acc[WTM][WTN];
#pragma unroll
  for (int i = 0; i < WTM; i++)
#pragma unroll
    for (int j = 0; j < WTN; j++)
#pragma unroll
      for (int r = 0; r < 4; r++) acc[i][j][r] = 0.f;

  const int srow = t >> 3;                       // 0..31 within a round
  const int scol = ((t & 7) ^ (srow & 7)) * 8;   // swizzled global k-chunk
  const unsigned short* Ab = A + (size_t)(m0 + srow) * K + scol + blockIdx.z * (size_t)kIters * BK;
  const unsigned short* Bb = Bt + (size_t)(n0 + srow) * K + scol + blockIdx.z * (size_t)kIters * BK;

  for (int it = 0; it < kIters; it++) {
    const int k0 = it * BK;
    __syncthreads();  // previous compute done with LDS
#pragma unroll
    for (int r = 0; r < RA; r++)
      gl2lds16(Ab + (size_t)r * 32 * K + k0, (const char*)lA + r * 4096 + t * 16);
#pragma unroll
    for (int r = 0; r < RB; r++)
      gl2lds16(Bb + (size_t)r * 32 * K + k0, (const char*)lB + r * 4096 + t * 16);
    __syncthreads();  // staging complete

#pragma unroll
    for (int s = 0; s < 2; s++) {   // two 16x16x32 k-steps per BK=64
      bf16x8 afr[WTM], bfr[WTN];
#pragma unroll
      for (int i = 0; i < WTM; i++) {
        int row = wm * (BM / 2) + i * 16 + l16;
        int slot = (s * 4 + quad) ^ (row & 7);
        afr[i] = __builtin_bit_cast(bf16x8, *(const int4*)(&lA[row * 64 + slot * 8]));
      }
#pragma unroll
      for (int j = 0; j < WTN; j++) {
        int row = wn * (BN / 2) + j * 16 + l16;
        int slot = (s * 4 + quad) ^ (row & 7);
        bfr[j] = __builtin_bit_cast(bf16x8, *(const int4*)(&lB[row * 64 + slot * 8]));
      }
#pragma unroll
      for (int i = 0; i < WTM; i++)
#pragma unroll
        for (int j = 0; j < WTN; j++)
          acc[i][j] = __builtin_amdgcn_mfma_f32_16x16x32_bf16(afr[i], bfr[j], acc[i][j], 0, 0, 0);
    }
  }

#pragma unroll
  for (int j = 0; j < WTN; j++) {
    const int col = n0 + wn * (BN / 2) + j * 16 + l16;
    const float bs = OUTF ? 0.f : bias[col];
#pragma unroll
    for (int i = 0; i < WTM; i++) {
#pragma unroll
      for (int r = 0; r < 4; r++) {
        int row = m0 + wm * (BM / 2) + i * 16 + quad * 4 + r;  // rows padded to MP
        if constexpr (OUTF) {
          float* p = (float*)C + (size_t)blockIdx.z * MP * Nsz + (size_t)row * Nsz + col;
          __builtin_nontemporal_store(acc[i][j][r], p);
        } else {
          unsigned short* p = (unsigned short*)C + (size_t)row * Nsz + col;
          __builtin_nontemporal_store(f2bf(acc[i][j][r] + bs), p);
        }
      }
    }
  }
}

// ---------------- combine split-K partials + bias -> qkvs2 -------------------
__global__ void combine2_k(const float* __restrict__ part, const float* __restrict__ bcat2,
                           float* __restrict__ qkvs2) {
  const int i = blockIdx.x * 256 + threadIdx.x;  // float4 index
  const float4 a = ((const float4*)part)[i];
  const float4 b = ((const float4*)(part + (size_t)MP * NCAT2))[i];
  const float4 c = ((const float4*)(part + (size_t)2 * MP * NCAT2))[i];
  const float4 d = ((const float4*)(part + (size_t)3 * MP * NCAT2))[i];
  const float4 bs = ((const float4*)bcat2)[i & 63];
  float4 o;
  o.x = a.x + b.x + c.x + d.x + bs.x;
  o.y = a.y + b.y + c.y + d.y + bs.y;
  o.z = a.z + b.z + c.z + d.z + bs.z;
  o.w = a.w + b.w + c.w + d.w + bs.w;
  ((float4*)qkvs2)[i] = o;
}

// ---------------- attention conv1: one block per (node, head) ----------------
__global__ __launch_bounds__(256) void attn1_k(const unsigned short* __restrict__ qkvs,
                                               const int* __restrict__ offs,
                                               const int* __restrict__ psrc,
                                               unsigned short* __restrict__ h1) {
  const int bid = blockIdx.x;
  const int xcd = bid & 7, idx = bid >> 3;       // idx 0..1679
  const int head = idx / 840;
  const int r2 = idx - head * 840;
  const int g = xcd * 2 + r2 / 420;
  const int n = g * 420 + r2 % 420;
  const int t = threadIdx.x, w = t >> 6, lane = t & 63;
  __shared__ __align__(16) unsigned short s_q[1024];
  __shared__ float s_al[64];
  __shared__ int s_src[64];
  __shared__ float s_m, s_l, s_sc;
  const size_t base = (size_t)n * NCAT1;
  const size_t ho = (size_t)head * 1024;
  *(ushort4*)(s_q + t * 4) = *(const ushort4*)(qkvs + base + ho + t * 4);
  float acc[4] = {0.f, 0.f, 0.f, 0.f};
  if (t == 0) { s_m = -1e30f; s_l = 0.f; }
  __syncthreads();
  const int e0 = offs[n], e1 = offs[n + 1];
  for (int c0 = e0; c0 < e1; c0 += 64) {
    const int ce = min(64, e1 - c0);
    if (t < ce) s_src[t] = psrc[c0 + t];
    __syncthreads();
    for (int e = w; e < ce; e += 4) {
      const unsigned short* kp = qkvs + (size_t)s_src[e] * NCAT1 + 2048 + ho;
      float p = 0.f;
#pragma unroll
      for (int i = 0; i < 2; i++) {
        u16x8 kv = *(const u16x8*)(kp + i * 512 + lane * 8);
        u16x8 qv = *(const u16x8*)(s_q + i * 512 + lane * 8);
#pragma unroll
        for (int j = 0; j < 8; j++) p += bf2f(qv[j]) * bf2f(kv[j]);
      }
#pragma unroll
      for (int s = 32; s > 0; s >>= 1) p += __shfl_xor(p, s, 64);
      if (lane == 0) s_al[e] = p * 0.03125f;  // 1/sqrt(1024)
    }
    __syncthreads();
    if (t == 0) {  // online-softmax combine (deg ~8, serial is fine)
      float mo = s_m, mn = mo;
      for (int e = 0; e < ce; e++) mn = fmaxf(mn, s_al[e]);
      float sc = __expf(mo - mn);
      float l = s_l * sc;
      for (int e = 0; e < ce; e++) {
        float we = __expf(s_al[e] - mn);
        l += we;
        s_al[e] = we;
      }
      s_m = mn; s_l = l; s_sc = sc;
    }
    __syncthreads();
    const float sc = s_sc;
#pragma unroll
    for (int j = 0; j < 4; j++) acc[j] *= sc;
    for (int e = 0; e < ce; e++) {
      const unsigned short* vp = qkvs + (size_t)s_src[e] * NCAT1 + 4096 + ho;
      const float we = s_al[e];
      ushort4 vv = *(const ushort4*)(vp + t * 4);
      acc[0] += we * bf2f(vv.x);
      acc[1] += we * bf2f(vv.y);
      acc[2] += we * bf2f(vv.z);
      acc[3] += we * bf2f(vv.w);
    }
    __syncthreads();
  }
  const float inv = 1.f / (s_l + 1e-16f);
  ushort4 sk = *(const ushort4*)(qkvs + base + 6144 + ho + t * 4);
  ushort4 o;
  o.x = f2bf(fmaxf(acc[0] * inv + bf2f(sk.x), 0.f));
  o.y = f2bf(fmaxf(acc[1] * inv + bf2f(sk.y), 0.f));
  o.z = f2bf(fmaxf(acc[2] * inv + bf2f(sk.z), 0.f));
  o.w = f2bf(fmaxf(acc[3] * inv + bf2f(sk.w), 0.f));
  *(ushort4*)(h1 + (size_t)n * 2048 + ho + t * 4) = o;
}

// ---------------- attention conv2: heads=1, d=64 (one wave per node) ---------
__global__ __launch_bounds__(64) void attn2_k(const float* __restrict__ qkvs2,
                                              const int* __restrict__ offs,
                                              const int* __restrict__ psrc,
                                              float* __restrict__ h2) {
  const int bid = blockIdx.x;
  const int xcd = bid & 7, idx = bid >> 3;  // idx 0..839
  const int g = xcd * 2 + idx / 420;
  const int n = g * 420 + idx % 420;
  const int t = threadIdx.x;
  const size_t rb = (size_t)n * NCAT2;
  const float q = qkvs2[rb + t];
  float m = -1e30f, l = 0.f, acc = 0.f;
  const int e0 = offs[n], e1 = offs[n + 1];
  for (int e = e0; e < e1; e++) {
    const int src = psrc[e];
    float p = q * qkvs2[(size_t)src * NCAT2 + 64 + t];
#pragma unroll
    for (int s = 32; s > 0; s >>= 1) p += __shfl_xor(p, s, 64);
    p *= 0.125f;  // 1/sqrt(64)
    const float mn = fmaxf(m, p);
    const float sc = __expf(m - mn), we = __expf(p - mn);
    const float v = qkvs2[(size_t)src * NCAT2 + 128 + t];
    l = l * sc + we;
    acc = acc * sc + we * v;
    m = mn;
  }
  float o = acc / (l + 1e-16f) + qkvs2[rb + 192 + t];  // + skip
  h2[(size_t)n * 64 + t] = fmaxf(o, 0.f);              // relu
}

// ---------------- fc1: [16,26880]@[26880,256], split-K atomics ---------------
__global__ __launch_bounds__(256) void fc1_k(const float* __restrict__ h2,
                                             const float* __restrict__ W,
                                             float* __restrict__ f1) {
  __shared__ float sA[16][256];
  const int t = threadIdx.x, k0 = blockIdx.x * 256;
#pragma unroll
  for (int r = 0; r < 16; r++) sA[r][t] = h2[(size_t)r * 26880 + k0 + t];
  __syncthreads();
  float acc[16];
#pragma unroll
  for (int r = 0; r < 16; r++) acc[r] = 0.f;
  for (int kk = 0; kk < 256; kk++) {
    const float wv = W[(size_t)(k0 + kk) * 256 + t];
#pragma unroll
    for (int r = 0; r < 16; r++) acc[r] += sA[r][kk] * wv;
  }
#pragma unroll
  for (int r = 0; r < 16; r++) atomicAdd(&f1[r * 256 + t], acc[r]);
}

// ---------------- fc2+fc3+fc4 fused: one block per batch row -----------------
__global__ __launch_bounds__(128) void fc234_k(const float* __restrict__ f1,
                                               const float* __restrict__ W2, const float* __restrict__ b2,
                                               const float* __restrict__ W3, const float* __restrict__ b3,
                                               const float* __restrict__ W4, const float* __restrict__ b4,
                                               float* __restrict__ out) {
  const int row = blockIdx.x, t = threadIdx.x;
  __shared__ float s2[128], s3[64];
  float acc = 0.f;
  for (int k = 0; k < 256; k++) acc += fmaxf(f1[row * 256 + k], 0.f) * W2[k * 128 + t];
  s2[t] = fmaxf(acc + b2[t], 0.f);
  __syncthreads();
  if (t < 64) {
    float a3 = 0.f;
    for (int k = 0; k < 128; k++) a3 += s2[k] * W3[k * 64 + t];
    s3[t] = fmaxf(a3 + b3[t], 0.f);
  }
  __syncthreads();
  if (t < 18) {
    float a4 = 0.f;
    for (int k = 0; k < 64; k++) a4 += s3[k] * W4[k * 18 + t];
    out[row * 18 + t] = a4 + b4[t];
  }
}

// ---------------------------------------------------------------------------
extern "C" void kernel_launch(void* const* d_in, const int* in_sizes, int n_in,
                              void* d_out, int out_size, void* d_ws, size_t ws_size,
                              hipStream_t stream) {
  const float* x    = (const float*)d_in[0];
  const int*   ei   = (const int*)d_in[1];
  const int*   conn = (const int*)d_in[2];
  const float* npe  = (const float*)d_in[3];
  const float* lpe  = (const float*)d_in[4];
  const float* gpe  = (const float*)d_in[5];
  const float* Wq1 = (const float*)d_in[6];  const float* bq1 = (const float*)d_in[7];
  const float* Wk1 = (const float*)d_in[8];  const float* bk1 = (const float*)d_in[9];
  const float* Wv1 = (const float*)d_in[10]; const float* bv1 = (const float*)d_in[11];
  const float* Ws1 = (const float*)d_in[12]; const float* bs1 = (const float*)d_in[13];
  const float* Wq2 = (const float*)d_in[14]; const float* bq2 = (const float*)d_in[15];
  const float* Wk2 = (const float*)d_in[16]; const float* bk2 = (const float*)d_in[17];
  const float* Wv2 = (const float*)d_in[18]; const float* bv2 = (const float*)d_in[19];
  const float* Ws2 = (const float*)d_in[20]; const float* bs2 = (const float*)d_in[21];
  const float* Wf1 = (const float*)d_in[22]; const float* bf1 = (const float*)d_in[23];
  const float* Wf2 = (const float*)d_in[24]; const float* bf2 = (const float*)d_in[25];
  const float* Wf3 = (const float*)d_in[26]; const float* bf3 = (const float*)d_in[27];
  const float* Wf4 = (const float*)d_in[28]; const float* bf4 = (const float*)d_in[29];
  float* out = (float*)d_out;

  char* ws = (char*)d_ws;
  size_t off = 0;
  auto alloc = [&](size_t bytes) -> void* {
    void* p = ws + off;
    off += (bytes + 255) & ~(size_t)255;
    return p;
  };
  unsigned short* h0    = (unsigned short*)alloc((size_t)MP * IN_DIM * 2);     // 27.8 MB
  unsigned short* w1t   = (unsigned short*)alloc((size_t)NCAT1 * KDIM * 2);    // 33.6 MB
  unsigned short* qkvs1 = (unsigned short*)alloc((size_t)MP * NCAT1 * 2);      // 111 MB
  unsigned short* w2t   = (unsigned short*)alloc((size_t)NCAT2 * KDIM * 2);    // 1 MB
  float* qkvs2 = (float*)alloc((size_t)MP * NCAT2 * 4);                        // 7 MB
  float* h2    = (float*)alloc((size_t)NN * 64 * 4);
  float* bcat1 = (float*)alloc(NCAT1 * 4);
  float* bcat2 = (float*)alloc(NCAT2 * 4);
  float* f1    = (float*)alloc(16 * 256 * 4);
  int* cnt    = (int*)alloc(NN * 4);
  int* offs   = (int*)alloc((NN + 1) * 4);
  int* cursor = (int*)alloc(NN * 4);
  int* psrc   = (int*)alloc(EE * 4);
  // h1 aliases w1t (weights dead after GEMM1, h1 written strictly after).
  unsigned short* h1 = w1t;
  // gemm2 split-K partials alias h0 (dead after GEMM1): 4*MP*256*4B == MP*2048*2B.
  float* part2 = (float*)h0;

  prep_k<<<32, 256, 0, stream>>>(cnt, bcat1, bcat2, f1,
                                 bq1, bk1, bv1, bs1, bq2, bk2, bv2, bs2, bf1);
  cnt_edges_k<<<EE / 256, 256, 0, stream>>>(ei, cnt);
  scan_offs_k<<<1, 256, 0, stream>>>(cnt, offs, cursor);
  scatter_k<<<EE / 256, 256, 0, stream>>>(ei, cursor, psrc);
  pe_add_k<<<NN, 256, 0, stream>>>(x, conn, npe, lpe, gpe, h0);
  transw_k<<<dim3(64, 64, 5), dim3(32, 8), 0, stream>>>(
      Wq1, Wk1, Wv1, Ws1, Wq2, Wk2, Wv2, Ws2, w1t, w2t);
  gemm_bt_k<128, 128, 0><<<dim3(NCAT1 / 128, MP / 128, 1), 256, 0, stream>>>(
      h0, w1t, bcat1, qkvs1, NCAT1, KDIM, KDIM / 64);
  attn1_k<<<2 * NN, 256, 0, stream>>>(qkvs1, offs, psrc, h1);
  gemm_bt_k<64, 64, 1><<<dim3(NCAT2 / 64, MP / 64, 4), 256, 0, stream>>>(
      h1, w2t, nullptr, part2, NCAT2, KDIM, KDIM / 64 / 4);
  combine2_k<<<MP / 4, 256, 0, stream>>>(part2, bcat2, qkvs2);
  attn2_k<<<NN, 64, 0, stream>>>(qkvs2, offs, psrc, h2);
  fc1_k<<<26880 / 256, 256, 0, stream>>>(h2, Wf1, f1);
  fc234_k<<<16, 128, 0, stream>>>(f1, Wf2, bf2, Wf3, bf3, Wf4, bf4, out);
}

// Round 5
// 576.276 us; speedup vs baseline: 1.0993x; 1.0993x over previous
//
#include <hip/hip_runtime.h>
#include <stdint.h>

#define N_GRAPHS 16
#define NODES_PER 420
#define NN (N_GRAPHS * NODES_PER)   // 6720 nodes
#define MP 6784                     // padded rows: 53 * 128
#define EE (NN * 8)                 // 53760 edges
#define IN_DIM 2048
#define NCAT1 8192                  // 4 * 2048  (Q|K|V|S)
#define NCAT2 256                   // 4 * 64
#define KDIM 2048

typedef __bf16 bf16x8 __attribute__((ext_vector_type(8)));
typedef float f32x4 __attribute__((ext_vector_type(4)));
typedef unsigned short u16x8 __attribute__((ext_vector_type(8)));

__device__ __forceinline__ unsigned short f2bf(float f) {
  unsigned u = __float_as_uint(f);
  u += 0x7FFFu + ((u >> 16) & 1u);   // round-to-nearest-even
  return (unsigned short)(u >> 16);
}
__device__ __forceinline__ float bf2f(unsigned short h) {
  return __uint_as_float(((unsigned)h) << 16);
}

// async global->LDS, 16B per lane. LDS dest must be wave-uniform base + lane*16.
__device__ __forceinline__ void gl2lds16(const void* g, const void* l) {
  __builtin_amdgcn_global_load_lds(
      (const __attribute__((address_space(1))) void*)(uintptr_t)g,
      (__attribute__((address_space(3))) void*)(unsigned int)(uintptr_t)l,
      16, 0, 0);
}

// ------- prep: zero counts, concat bias1/bias2, init f1 with bias -----------
__global__ void prep_k(int* cnt, float* bcat1, float* bcat2, float* f1,
                       const float* bq1, const float* bk1, const float* bv1, const float* bs1,
                       const float* bq2, const float* bk2, const float* bv2, const float* bs2,
                       const float* bfc1) {
  int i = blockIdx.x * 256 + threadIdx.x;
  if (i < NN) cnt[i] = 0;
  if (i < NCAT1) {
    const float* p = i < 2048 ? bq1 : i < 4096 ? bk1 : i < 6144 ? bv1 : bs1;
    bcat1[i] = p[i & 2047];
  }
  if (i < NCAT2) {
    const float* p = i < 64 ? bq2 : i < 128 ? bk2 : i < 192 ? bv2 : bs2;
    bcat2[i] = p[i & 63];
  }
  if (i < 16 * 256) f1[i] = bfc1[i & 255];
}

// ---------------- CSR build --------------------------------------------------
__global__ void cnt_edges_k(const int* __restrict__ ei, int* __restrict__ cnt) {
  int e = blockIdx.x * 256 + threadIdx.x;
  if (e < EE) atomicAdd(&cnt[ei[EE + e]], 1);
}

// 256 threads, thread owns 27 nodes; shfl wave scan + cross-wave LDS scan.
__global__ __launch_bounds__(256) void scan_offs_k(const int* __restrict__ cnt,
                                                   int* __restrict__ offs,
                                                   int* __restrict__ cursor) {
  const int t = threadIdx.x;
  const int base = t * 27;
  int c[27];
  int s = 0;
#pragma unroll
  for (int j = 0; j < 27; j++) {
    int idx = base + j;
    c[j] = idx < NN ? cnt[idx] : 0;
    s += c[j];
  }
  const int lane = t & 63, w = t >> 6;
  int pfx = s;  // inclusive wave scan
#pragma unroll
  for (int d = 1; d < 64; d <<= 1) {
    int v = __shfl_up(pfx, d, 64);
    if (lane >= d) pfx += v;
  }
  __shared__ int wtot[4];
  if (lane == 63) wtot[w] = pfx;
  __syncthreads();
  int add = 0;
#pragma unroll
  for (int i = 0; i < 4; i++)
    if (i < w) add += wtot[i];
  int run = add + pfx - s;  // exclusive prefix
#pragma unroll
  for (int j = 0; j < 27; j++) {
    int idx = base + j;
    if (idx < NN) { offs[idx] = run; cursor[idx] = run; }
    run += c[j];
  }
  if (t == 255) offs[NN] = add + pfx;  // grand total
}

__global__ void scatter_k(const int* __restrict__ ei, int* __restrict__ cursor,
                          int* __restrict__ psrc) {
  int e = blockIdx.x * 256 + threadIdx.x;
  if (e < EE) {
    int d = ei[EE + e];
    int pos = atomicAdd(&cursor[d], 1);
    psrc[pos] = ei[e];
  }
}

// ------- positional-embedding add fp32->bf16 --------------------------------
__global__ void pe_add_k(const float* __restrict__ x, const int* __restrict__ conn,
                         const float* __restrict__ npe, const float* __restrict__ lpe,
                         const float* __restrict__ gpe, unsigned short* __restrict__ h0) {
  const int n = blockIdx.x, t = threadIdx.x;
  const int c = conn[n];
  const float4* x4 = (const float4*)(x + (size_t)n * IN_DIM);
  const float4* n4 = (const float4*)(npe + (size_t)(n % NODES_PER) * IN_DIM);
  const float4* l4 = (const float4*)(lpe + (size_t)(c - 1) * IN_DIM);
  const float4* g4 = (const float4*)(gpe + (size_t)(c <= 2 ? 0 : 1) * IN_DIM);
  ushort4* o4 = (ushort4*)(h0 + (size_t)n * IN_DIM);
#pragma unroll
  for (int i = 0; i < 2; i++) {
    int idx = i * 256 + t;
    float4 a = x4[idx], b = n4[idx], cc = l4[idx], d = g4[idx];
    ushort4 o;
    o.x = f2bf(a.x + b.x + cc.x + d.x);
    o.y = f2bf(a.y + b.y + cc.y + d.y);
    o.z = f2bf(a.z + b.z + cc.z + d.z);
    o.w = f2bf(a.w + b.w + cc.w + d.w);
    o4[idx] = o;
  }
}

// ---------------- weight transpose + bf16 convert: W[K,Nc] -> Wt[Nc,K] -------
__global__ void transw_k(const float* Wq1, const float* Wk1, const float* Wv1, const float* Ws1,
                         const float* Wq2, const float* Wk2, const float* Wv2, const float* Ws2,
                         unsigned short* __restrict__ o1, unsigned short* __restrict__ o2) {
  __shared__ float tile[32][33];
  const int z = blockIdx.z;
  const float* W;
  unsigned short* o;
  int n0, Ncol;
  const int k0 = blockIdx.y * 32;
  if (z < 4) {
    W = z == 0 ? Wq1 : z == 1 ? Wk1 : z == 2 ? Wv1 : Ws1;
    o = o1 + (size_t)z * 2048 * KDIM;
    n0 = blockIdx.x * 32; Ncol = 2048;
  } else {
    if (blockIdx.x >= 8) return;
    const int m = blockIdx.x >> 1;
    W = m == 0 ? Wq2 : m == 1 ? Wk2 : m == 2 ? Wv2 : Ws2;
    o = o2 + (size_t)m * 64 * KDIM;
    n0 = (blockIdx.x & 1) * 32; Ncol = 64;
  }
  const int tx = threadIdx.x, ty = threadIdx.y;
#pragma unroll
  for (int r = 0; r < 4; r++)
    tile[ty + r * 8][tx] = W[(size_t)(k0 + ty + r * 8) * Ncol + n0 + tx];
  __syncthreads();
#pragma unroll
  for (int r = 0; r < 4; r++)
    o[(size_t)(n0 + ty + r * 8) * KDIM + k0 + tx] = f2bf(tile[tx][ty + r * 8]);
}

// ---------------- bf16 MFMA GEMM, C = A @ Bt^T + bias ------------------------
// A [Mpad,K] bf16 row-major, Bt [N,K] bf16 row-major. BK=64, 2-barrier K-loop,
// global_load_lds x16B with k-chunk XOR swizzle (bank-conflict-free ds_read).
// OUTF==0: C bf16. OUTF==1: C f32.  (round-3 proven config: lb(256,3), plain stores)
template <int BM, int BN, int OUTF>
__launch_bounds__(256, 3)
__global__ void gemm_bt_k(const unsigned short* __restrict__ A,
                          const unsigned short* __restrict__ Bt,
                          const float* __restrict__ bias, void* __restrict__ C,
                          int Nsz, int K, int kIters) {
  constexpr int BK = 64;
  constexpr int WTM = BM / 32, WTN = BN / 32;  // MFMA tiles per wave (2x2 wave grid)
  constexpr int RA = BM / 32, RB = BN / 32;    // 4KB staging rounds (32 rows each)
  __shared__ __align__(16) unsigned short lA[BM * BK];
  __shared__ __align__(16) unsigned short lB[BN * BK];
  const int t = threadIdx.x;
  const int w = t >> 6, lane = t & 63;
  const int wm = w >> 1, wn = w & 1;
  const int quad = lane >> 4, l16 = lane & 15;
  const int m0 = blockIdx.y * BM, n0 = blockIdx.x * BN;

  f32x4 acc[WTM][WTN];
#pragma unroll
  for (int i = 0; i < WTM; i++)
#pragma unroll
    for (int j = 0; j < WTN; j++)
#pragma unroll
      for (int r = 0; r < 4; r++) acc[i][j][r] = 0.f;

  const int srow = t >> 3;                       // 0..31 within a round
  const int scol = ((t & 7) ^ (srow & 7)) * 8;   // swizzled global k-chunk
  const unsigned short* Ab = A + (size_t)(m0 + srow) * K + scol;
  const unsigned short* Bb = Bt + (size_t)(n0 + srow) * K + scol;

  for (int it = 0; it < kIters; it++) {
    const int k0 = it * BK;
    __syncthreads();  // previous compute done with LDS
#pragma unroll
    for (int r = 0; r < RA; r++)
      gl2lds16(Ab + (size_t)r * 32 * K + k0, (const char*)lA + r * 4096 + t * 16);
#pragma unroll
    for (int r = 0; r < RB; r++)
      gl2lds16(Bb + (size_t)r * 32 * K + k0, (const char*)lB + r * 4096 + t * 16);
    __syncthreads();  // staging complete

#pragma unroll
    for (int s = 0; s < 2; s++) {   // two 16x16x32 k-steps per BK=64
      bf16x8 afr[WTM], bfr[WTN];
#pragma unroll
      for (int i = 0; i < WTM; i++) {
        int row = wm * (BM / 2) + i * 16 + l16;
        int slot = (s * 4 + quad) ^ (row & 7);
        afr[i] = __builtin_bit_cast(bf16x8, *(const int4*)(&lA[row * 64 + slot * 8]));
      }
#pragma unroll
      for (int j = 0; j < WTN; j++) {
        int row = wn * (BN / 2) + j * 16 + l16;
        int slot = (s * 4 + quad) ^ (row & 7);
        bfr[j] = __builtin_bit_cast(bf16x8, *(const int4*)(&lB[row * 64 + slot * 8]));
      }
#pragma unroll
      for (int i = 0; i < WTM; i++)
#pragma unroll
        for (int j = 0; j < WTN; j++)
          acc[i][j] = __builtin_amdgcn_mfma_f32_16x16x32_bf16(afr[i], bfr[j], acc[i][j], 0, 0, 0);
    }
  }

#pragma unroll
  for (int j = 0; j < WTN; j++) {
    const int col = n0 + wn * (BN / 2) + j * 16 + l16;
    const float bs = bias[col];
#pragma unroll
    for (int i = 0; i < WTM; i++) {
#pragma unroll
      for (int r = 0; r < 4; r++) {
        int row = m0 + wm * (BM / 2) + i * 16 + quad * 4 + r;  // rows padded to MP
        float v = acc[i][j][r] + bs;
        if constexpr (OUTF)
          ((float*)C)[(size_t)row * Nsz + col] = v;
        else
          ((unsigned short*)C)[(size_t)row * Nsz + col] = f2bf(v);
      }
    }
  }
}

// ---------------- attention conv1: one block per (node, head) ----------------
// XCD-aware mapping: per-XCD KV working set = 2 graphs x 1 head ~ 3.4MB < L2.
__global__ __launch_bounds__(256) void attn1_k(const unsigned short* __restrict__ qkvs,
                                               const int* __restrict__ offs,
                                               const int* __restrict__ psrc,
                                               unsigned short* __restrict__ h1) {
  const int bid = blockIdx.x;
  const int xcd = bid & 7, idx = bid >> 3;       // idx 0..1679
  const int head = idx / 840;
  const int r2 = idx - head * 840;
  const int g = xcd * 2 + r2 / 420;
  const int n = g * 420 + r2 % 420;
  const int t = threadIdx.x, w = t >> 6, lane = t & 63;
  __shared__ __align__(16) unsigned short s_q[1024];
  __shared__ float s_al[64];
  __shared__ int s_src[64];
  __shared__ float s_m, s_l, s_sc;
  const size_t base = (size_t)n * NCAT1;
  const size_t ho = (size_t)head * 1024;
  *(ushort4*)(s_q + t * 4) = *(const ushort4*)(qkvs + base + ho + t * 4);
  float acc[4] = {0.f, 0.f, 0.f, 0.f};
  if (t == 0) { s_m = -1e30f; s_l = 0.f; }
  __syncthreads();
  const int e0 = offs[n], e1 = offs[n + 1];
  for (int c0 = e0; c0 < e1; c0 += 64) {
    const int ce = min(64, e1 - c0);
    if (t < ce) s_src[t] = psrc[c0 + t];
    __syncthreads();
    for (int e = w; e < ce; e += 4) {
      const unsigned short* kp = qkvs + (size_t)s_src[e] * NCAT1 + 2048 + ho;
      float p = 0.f;
#pragma unroll
      for (int i = 0; i < 2; i++) {
        u16x8 kv = *(const u16x8*)(kp + i * 512 + lane * 8);
        u16x8 qv = *(const u16x8*)(s_q + i * 512 + lane * 8);
#pragma unroll
        for (int j = 0; j < 8; j++) p += bf2f(qv[j]) * bf2f(kv[j]);
      }
#pragma unroll
      for (int s = 32; s > 0; s >>= 1) p += __shfl_xor(p, s, 64);
      if (lane == 0) s_al[e] = p * 0.03125f;  // 1/sqrt(1024)
    }
    __syncthreads();
    if (t == 0) {  // online-softmax combine (deg ~8, serial is fine)
      float mo = s_m, mn = mo;
      for (int e = 0; e < ce; e++) mn = fmaxf(mn, s_al[e]);
      float sc = __expf(mo - mn);
      float l = s_l * sc;
      for (int e = 0; e < ce; e++) {
        float we = __expf(s_al[e] - mn);
        l += we;
        s_al[e] = we;
      }
      s_m = mn; s_l = l; s_sc = sc;
    }
    __syncthreads();
    const float sc = s_sc;
#pragma unroll
    for (int j = 0; j < 4; j++) acc[j] *= sc;
    for (int e = 0; e < ce; e++) {
      const unsigned short* vp = qkvs + (size_t)s_src[e] * NCAT1 + 4096 + ho;
      const float we = s_al[e];
      ushort4 vv = *(const ushort4*)(vp + t * 4);
      acc[0] += we * bf2f(vv.x);
      acc[1] += we * bf2f(vv.y);
      acc[2] += we * bf2f(vv.z);
      acc[3] += we * bf2f(vv.w);
    }
    __syncthreads();
  }
  const float inv = 1.f / (s_l + 1e-16f);
  ushort4 sk = *(const ushort4*)(qkvs + base + 6144 + ho + t * 4);
  ushort4 o;
  o.x = f2bf(fmaxf(acc[0] * inv + bf2f(sk.x), 0.f));
  o.y = f2bf(fmaxf(acc[1] * inv + bf2f(sk.y), 0.f));
  o.z = f2bf(fmaxf(acc[2] * inv + bf2f(sk.z), 0.f));
  o.w = f2bf(fmaxf(acc[3] * inv + bf2f(sk.w), 0.f));
  *(ushort4*)(h1 + (size_t)n * 2048 + ho + t * 4) = o;
}

// ---------------- attention conv2: heads=1, d=64 (one wave per node) ---------
__global__ __launch_bounds__(64) void attn2_k(const float* __restrict__ qkvs2,
                                              const int* __restrict__ offs,
                                              const int* __restrict__ psrc,
                                              float* __restrict__ h2) {
  const int bid = blockIdx.x;
  const int xcd = bid & 7, idx = bid >> 3;  // idx 0..839
  const int g = xcd * 2 + idx / 420;
  const int n = g * 420 + idx % 420;
  const int t = threadIdx.x;
  const size_t rb = (size_t)n * NCAT2;
  const float q = qkvs2[rb + t];
  float m = -1e30f, l = 0.f, acc = 0.f;
  const int e0 = offs[n], e1 = offs[n + 1];
  for (int e = e0; e < e1; e++) {
    const int src = psrc[e];
    float p = q * qkvs2[(size_t)src * NCAT2 + 64 + t];
#pragma unroll
    for (int s = 32; s > 0; s >>= 1) p += __shfl_xor(p, s, 64);
    p *= 0.125f;  // 1/sqrt(64)
    const float mn = fmaxf(m, p);
    const float sc = __expf(m - mn), we = __expf(p - mn);
    const float v = qkvs2[(size_t)src * NCAT2 + 128 + t];
    l = l * sc + we;
    acc = acc * sc + we * v;
    m = mn;
  }
  float o = acc / (l + 1e-16f) + qkvs2[rb + 192 + t];  // + skip
  h2[(size_t)n * 64 + t] = fmaxf(o, 0.f);              // relu
}

// ---------------- fc1: [16,26880]@[26880,256], split-K atomics ---------------
__global__ __launch_bounds__(256) void fc1_k(const float* __restrict__ h2,
                                             const float* __restrict__ W,
                                             float* __restrict__ f1) {
  __shared__ float sA[16][256];
  const int t = threadIdx.x, k0 = blockIdx.x * 256;
#pragma unroll
  for (int r = 0; r < 16; r++) sA[r][t] = h2[(size_t)r * 26880 + k0 + t];
  __syncthreads();
  float acc[16];
#pragma unroll
  for (int r = 0; r < 16; r++) acc[r] = 0.f;
  for (int kk = 0; kk < 256; kk++) {
    const float wv = W[(size_t)(k0 + kk) * 256 + t];
#pragma unroll
    for (int r = 0; r < 16; r++) acc[r] += sA[r][kk] * wv;
  }
#pragma unroll
  for (int r = 0; r < 16; r++) atomicAdd(&f1[r * 256 + t], acc[r]);
}

// ---------------- fc2+fc3+fc4 fused: one block per batch row -----------------
__global__ __launch_bounds__(128) void fc234_k(const float* __restrict__ f1,
                                               const float* __restrict__ W2, const float* __restrict__ b2,
                                               const float* __restrict__ W3, const float* __restrict__ b3,
                                               const float* __restrict__ W4, const float* __restrict__ b4,
                                               float* __restrict__ out) {
  const int row = blockIdx.x, t = threadIdx.x;
  __shared__ float s2[128], s3[64];
  float acc = 0.f;
  for (int k = 0; k < 256; k++) acc += fmaxf(f1[row * 256 + k], 0.f) * W2[k * 128 + t];
  s2[t] = fmaxf(acc + b2[t], 0.f);
  __syncthreads();
  if (t < 64) {
    float a3 = 0.f;
    for (int k = 0; k < 128; k++) a3 += s2[k] * W3[k * 64 + t];
    s3[t] = fmaxf(a3 + b3[t], 0.f);
  }
  __syncthreads();
  if (t < 18) {
    float a4 = 0.f;
    for (int k = 0; k < 64; k++) a4 += s3[k] * W4[k * 18 + t];
    out[row * 18 + t] = a4 + b4[t];
  }
}

// ---------------------------------------------------------------------------
extern "C" void kernel_launch(void* const* d_in, const int* in_sizes, int n_in,
                              void* d_out, int out_size, void* d_ws, size_t ws_size,
                              hipStream_t stream) {
  const float* x    = (const float*)d_in[0];
  const int*   ei   = (const int*)d_in[1];
  const int*   conn = (const int*)d_in[2];
  const float* npe  = (const float*)d_in[3];
  const float* lpe  = (const float*)d_in[4];
  const float* gpe  = (const float*)d_in[5];
  const float* Wq1 = (const float*)d_in[6];  const float* bq1 = (const float*)d_in[7];
  const float* Wk1 = (const float*)d_in[8];  const float* bk1 = (const float*)d_in[9];
  const float* Wv1 = (const float*)d_in[10]; const float* bv1 = (const float*)d_in[11];
  const float* Ws1 = (const float*)d_in[12]; const float* bs1 = (const float*)d_in[13];
  const float* Wq2 = (const float*)d_in[14]; const float* bq2 = (const float*)d_in[15];
  const float* Wk2 = (const float*)d_in[16]; const float* bk2 = (const float*)d_in[17];
  const float* Wv2 = (const float*)d_in[18]; const float* bv2 = (const float*)d_in[19];
  const float* Ws2 = (const float*)d_in[20]; const float* bs2 = (const float*)d_in[21];
  const float* Wf1 = (const float*)d_in[22]; const float* bf1 = (const float*)d_in[23];
  const float* Wf2 = (const float*)d_in[24]; const float* bf2 = (const float*)d_in[25];
  const float* Wf3 = (const float*)d_in[26]; const float* bf3 = (const float*)d_in[27];
  const float* Wf4 = (const float*)d_in[28]; const float* bf4 = (const float*)d_in[29];
  float* out = (float*)d_out;

  char* ws = (char*)d_ws;
  size_t off = 0;
  auto alloc = [&](size_t bytes) -> void* {
    void* p = ws + off;
    off += (bytes + 255) & ~(size_t)255;
    return p;
  };
  unsigned short* h0    = (unsigned short*)alloc((size_t)MP * IN_DIM * 2);     // 27.8 MB
  unsigned short* w1t   = (unsigned short*)alloc((size_t)NCAT1 * KDIM * 2);    // 33.6 MB
  unsigned short* qkvs1 = (unsigned short*)alloc((size_t)MP * NCAT1 * 2);      // 111 MB
  unsigned short* w2t   = (unsigned short*)alloc((size_t)NCAT2 * KDIM * 2);    // 1 MB
  float* qkvs2 = (float*)alloc((size_t)MP * NCAT2 * 4);                        // 7 MB
  float* h2    = (float*)alloc((size_t)NN * 64 * 4);
  float* bcat1 = (float*)alloc(NCAT1 * 4);
  float* bcat2 = (float*)alloc(NCAT2 * 4);
  float* f1    = (float*)alloc(16 * 256 * 4);
  int* cnt    = (int*)alloc(NN * 4);
  int* offs   = (int*)alloc((NN + 1) * 4);
  int* cursor = (int*)alloc(NN * 4);
  int* psrc   = (int*)alloc(EE * 4);
  // h1 aliases w1t (weights dead after GEMM1, h1 written strictly after).
  unsigned short* h1 = w1t;

  prep_k<<<32, 256, 0, stream>>>(cnt, bcat1, bcat2, f1,
                                 bq1, bk1, bv1, bs1, bq2, bk2, bv2, bs2, bf1);
  cnt_edges_k<<<EE / 256, 256, 0, stream>>>(ei, cnt);
  scan_offs_k<<<1, 256, 0, stream>>>(cnt, offs, cursor);
  scatter_k<<<EE / 256, 256, 0, stream>>>(ei, cursor, psrc);
  pe_add_k<<<NN, 256, 0, stream>>>(x, conn, npe, lpe, gpe, h0);
  transw_k<<<dim3(64, 64, 5), dim3(32, 8), 0, stream>>>(
      Wq1, Wk1, Wv1, Ws1, Wq2, Wk2, Wv2, Ws2, w1t, w2t);
  gemm_bt_k<128, 128, 0><<<dim3(NCAT1 / 128, MP / 128), 256, 0, stream>>>(
      h0, w1t, bcat1, qkvs1, NCAT1, KDIM, KDIM / 64);
  attn1_k<<<2 * NN, 256, 0, stream>>>(qkvs1, offs, psrc, h1);
  gemm_bt_k<64, 64, 1><<<dim3(NCAT2 / 64, MP / 64), 256, 0, stream>>>(
      h1, w2t, bcat2, qkvs2, NCAT2, KDIM, KDIM / 64);
  attn2_k<<<NN, 64, 0, stream>>>(qkvs2, offs, psrc, h2);
  fc1_k<<<26880 / 256, 256, 0, stream>>>(h2, Wf1, f1);
  fc234_k<<<16, 128, 0, stream>>>(f1, Wf2, bf2, Wf3, bf3, Wf4, bf4, out);
}